// Round 5
// baseline (257.918 us; speedup 1.0000x reference)
//
#include <hip/hip_runtime.h>
#include <hip/hip_bf16.h>

// Sizes
#define HD   256
#define TT   32
#define MV   4096
#define LD_  24
#define LP_  12
#define LM_  20
#define MAXNZ 96

typedef _Float16 h2v __attribute__((ext_vector_type(2)));
typedef _Float16 h8  __attribute__((ext_vector_type(8)));

__device__ __forceinline__ float fdot2(h2v a, h2v b, float c) {
#if __has_builtin(__builtin_amdgcn_fdot2)
  return __builtin_amdgcn_fdot2(a, b, c, false);
#else
  return c + (float)a[0] * (float)b[0] + (float)a[1] * (float)b[1];
#endif
}

#define PIN2(x) { float _t = __builtin_bit_cast(float, x); \
                  asm volatile("" : "+v"(_t));             \
                  x = __builtin_bit_cast(h2v, _t); }

// K0: whh (f32, 768x256 row-major) -> f16, transposed chunk layout:
// wt[b][i][row] = h8 of whh[b][row][8i..8i+7]  (i in [0,32), row in [0,768))
__global__ __launch_bounds__(768) void k0_cvt(
    const float* __restrict__ whh_d, const float* __restrict__ whh_p,
    h8* __restrict__ wt)
{
  const int i = blockIdx.x, b = blockIdx.y, g = threadIdx.x;
  const float* whh = b ? whh_p : whh_d;
  const float* src = whh + (size_t)g * HD + 8 * i;
  h8 v;
#pragma unroll
  for (int e = 0; e < 8; ++e) v[e] = (_Float16)src[e];
  wt[((size_t)b * 32 + i) * 768 + g] = v;
}

// K1: seq = sum of embedding rows; GI[b][t][g] = bih[g] + sum_k wih[g,k]*seq[k]
__global__ __launch_bounds__(768) void k1_embed_gi(
    const int* __restrict__ dc, const int* __restrict__ pc,
    const float* __restrict__ demb, const float* __restrict__ pemb,
    const float* __restrict__ wih_d, const float* __restrict__ bih_d,
    const float* __restrict__ wih_p, const float* __restrict__ bih_p,
    float* __restrict__ GI)
{
  const int t = blockIdx.x, b = blockIdx.y;
  const int* codes = b ? pc : dc;
  const int L = b ? LP_ : LD_;
  const float* emb = b ? pemb : demb;
  const float* wih = b ? wih_p : wih_d;
  const float* bih = b ? bih_p : bih_d;
  __shared__ float s[HD];
  const int j = threadIdx.x;
  if (j < HD) {
    float acc = 0.f;
    for (int l = 0; l < L; ++l) acc += emb[(size_t)codes[t * L + l] * HD + j];
    s[j] = acc;
  }
  __syncthreads();
  const int g = j;
  float acc = bih[g];
  const float* wr = wih + (size_t)g * HD;
  for (int k = 0; k < HD; k += 4) {
    float4 w4 = *(const float4*)(wr + k);
    acc = fmaf(w4.x, s[k], acc);
    acc = fmaf(w4.y, s[k + 1], acc);
    acc = fmaf(w4.z, s[k + 2], acc);
    acc = fmaf(w4.w, s[k + 3], acc);
  }
  GI[((size_t)b * TT + t) * 768 + g] = acc;
}

// K2: sequential GRU. 256 threads (4 waves = 1 wave/SIMD, VGPR budget 512).
// Each thread g owns ALL THREE gate rows (r,z,n) for h-dim g: 384 VGPRs of
// f16 weights, register-resident. No gh exchange needed; 1 barrier/step
// (double-buffered h in LDS). amdgpu_waves_per_eu(1,1) pins the occupancy
// target so the allocator uses the full register file instead of spilling.
__global__ __launch_bounds__(256)
__attribute__((amdgpu_waves_per_eu(1, 1)))
void k2_gru(
    const float* __restrict__ GI, const h8* __restrict__ wt,
    const float* __restrict__ bhh_d, const float* __restrict__ bhh_p,
    float* __restrict__ feats)
{
  const int b = blockIdx.x, g = threadIdx.x;  // g in [0,256)
  const float* gi = GI + (size_t)b * TT * 768;
  const float* bhh = b ? bhh_p : bhh_d;

  __shared__ h8 hbuf[2][32];  // h as packed f16, double-buffered

  h2v wr_[128], wz_[128], wn_[128];
  {
    const h8* wbase = wt + (size_t)b * 32 * 768;
#pragma unroll
    for (int i = 0; i < 32; ++i) {
      union { h8 v; h2v p[4]; } u;
      u.v = wbase[(size_t)i * 768 + g];
      wr_[4*i+0] = u.p[0]; wr_[4*i+1] = u.p[1];
      wr_[4*i+2] = u.p[2]; wr_[4*i+3] = u.p[3];
      u.v = wbase[(size_t)i * 768 + 256 + g];
      wz_[4*i+0] = u.p[0]; wz_[4*i+1] = u.p[1];
      wz_[4*i+2] = u.p[2]; wz_[4*i+3] = u.p[3];
      u.v = wbase[(size_t)i * 768 + 512 + g];
      wn_[4*i+0] = u.p[0]; wn_[4*i+1] = u.p[1];
      wn_[4*i+2] = u.p[2]; wn_[4*i+3] = u.p[3];
    }
  }
#pragma unroll
  for (int i = 0; i < 128; ++i) { PIN2(wr_[i]) PIN2(wz_[i]) PIN2(wn_[i]) }

  const float bh_r = bhh[g], bh_z = bhh[256 + g], bh_n = bhh[512 + g];
  float hreg = 0.f;
  ((_Float16*)&hbuf[0][0])[g] = (_Float16)0.f;
  __syncthreads();

  for (int t = 0; t < TT; ++t) {
    // prefetch gate inputs (independent of h): hidden under the dot loop
    const float* git = gi + t * 768;
    float ir = git[g], iz = git[256 + g], inn = git[512 + g];

    const h8* hb = hbuf[t & 1];
    float ar0 = 0.f, ar1 = 0.f, az0 = 0.f, az1 = 0.f, an0 = 0.f, an1 = 0.f;
#pragma unroll
    for (int i = 0; i < 32; ++i) {
      union { h8 v; h2v p[4]; } u;
      u.v = hb[i];
      ar0 = fdot2(wr_[4*i+0], u.p[0], ar0);
      ar1 = fdot2(wr_[4*i+1], u.p[1], ar1);
      ar0 = fdot2(wr_[4*i+2], u.p[2], ar0);
      ar1 = fdot2(wr_[4*i+3], u.p[3], ar1);
      az0 = fdot2(wz_[4*i+0], u.p[0], az0);
      az1 = fdot2(wz_[4*i+1], u.p[1], az1);
      az0 = fdot2(wz_[4*i+2], u.p[2], az0);
      az1 = fdot2(wz_[4*i+3], u.p[3], az1);
      an0 = fdot2(wn_[4*i+0], u.p[0], an0);
      an1 = fdot2(wn_[4*i+1], u.p[1], an1);
      an0 = fdot2(wn_[4*i+2], u.p[2], an0);
      an1 = fdot2(wn_[4*i+3], u.p[3], an1);
    }
    const float hr = ar0 + ar1 + bh_r;
    const float hz = az0 + az1 + bh_z;
    const float hn = an0 + an1 + bh_n;
    const float r = 1.f / (1.f + __expf(-(ir + hr)));
    const float z = 1.f / (1.f + __expf(-(iz + hz)));
    const float n = tanhf(inn + r * hn);
    hreg = (1.f - z) * n + z * hreg;
    ((_Float16*)&hbuf[(t & 1) ^ 1][0])[g] = (_Float16)hreg;
    feats[(size_t)t * 512 + b * HD + g] = hreg;
    __syncthreads();
  }
}

// K2b: queries[t,j] = q_b[j] + sum_k relu(feats[t,k]) * q_w[k,j]
__global__ __launch_bounds__(256) void k2b_queries(
    const float* __restrict__ feats, const float* __restrict__ q_w,
    const float* __restrict__ q_b, float* __restrict__ queries)
{
  const int t = blockIdx.x, j = threadIdx.x;
  __shared__ float f[512];
  f[j] = fmaxf(feats[(size_t)t * 512 + j], 0.f);
  f[j + 256] = fmaxf(feats[(size_t)t * 512 + 256 + j], 0.f);
  __syncthreads();
  float acc = q_b[j];
  for (int k = 0; k < 512; ++k) acc = fmaf(f[k], q_w[(size_t)k * HD + j], acc);
  queries[(size_t)t * HD + j] = acc;
}

// K3: one WAVE per adj row (64 lanes x 64 elems); shfl-based prefix scan,
// zero barriers; 8 rows per 512-thread block. Emits sparse (col,val) and
// h1[row,:] = relu(b1 + sum val*w1[col,:]).
__global__ __launch_bounds__(512) void k3_scan(
    const float* __restrict__ adj_e, const float* __restrict__ adj_d,
    const float* __restrict__ w1_e, const float* __restrict__ b1_e,
    const float* __restrict__ w1_d, const float* __restrict__ b1_d,
    float* __restrict__ h1, int* __restrict__ cnt_g,
    int* __restrict__ cols_g, float* __restrict__ vals_g)
{
  const int w = threadIdx.x >> 6, lane = threadIdx.x & 63;
  const int rg = blockIdx.x * 8 + w;          // [0, 16384)
  const int bsel = rg >> 12;
  const int r = rg & (MV - 1);
  const float* adj = (bsel ? adj_d : adj_e) + (size_t)r * MV;
  const float* w1 = bsel ? w1_d : w1_e;
  const float* b1 = bsel ? b1_d : b1_e;

  __shared__ int   scols[8][MAXNZ];
  __shared__ float svals[8][MAXNZ];

  float4 ev[16];
#pragma unroll
  for (int c = 0; c < 16; ++c)
    ev[c] = *(const float4*)(adj + c * 256 + lane * 4);

  int cl = 0;
#pragma unroll
  for (int c = 0; c < 16; ++c)
    cl += (ev[c].x != 0.f) + (ev[c].y != 0.f) + (ev[c].z != 0.f) + (ev[c].w != 0.f);

  int pref = cl;
#pragma unroll
  for (int ofs = 1; ofs < 64; ofs <<= 1) {
    int v = __shfl_up(pref, ofs, 64);
    if (lane >= ofs) pref += v;
  }
  const int total = __shfl(pref, 63, 64);
  int pos = pref - cl;  // exclusive prefix

#pragma unroll
  for (int c = 0; c < 16; ++c) {
    const float vv[4] = {ev[c].x, ev[c].y, ev[c].z, ev[c].w};
#pragma unroll
    for (int e = 0; e < 4; ++e) {
      if (vv[e] != 0.f) {
        if (pos < MAXNZ) {
          scols[w][pos] = c * 256 + lane * 4 + e;
          svals[w][pos] = vv[e];
        }
        ++pos;
      }
    }
  }
  const int n = total > MAXNZ ? MAXNZ : total;
  // wave-synchronous LDS (single producer/consumer wave, lockstep) -> no barrier

  float4 acc = *(const float4*)(b1 + lane * 4);
  for (int k = 0; k < n; ++k) {
    const int col = scols[w][k];
    const float v = svals[w][k];
    const float4 wv4 = *(const float4*)(w1 + (size_t)col * HD + lane * 4);
    acc.x = fmaf(v, wv4.x, acc.x);
    acc.y = fmaf(v, wv4.y, acc.y);
    acc.z = fmaf(v, wv4.z, acc.z);
    acc.w = fmaf(v, wv4.w, acc.w);
  }
  float4 hro;
  hro.x = fmaxf(acc.x, 0.f); hro.y = fmaxf(acc.y, 0.f);
  hro.z = fmaxf(acc.z, 0.f); hro.w = fmaxf(acc.w, 0.f);
  *(float4*)(h1 + (size_t)rg * HD + lane * 4) = hro;

  if (lane == 0) cnt_g[rg] = n;
  for (int k = lane; k < n; k += 64) {
    cols_g[(size_t)rg * MAXNZ + k] = scols[w][k];
    vals_g[(size_t)rg * MAXNZ + k] = svals[w][k];
  }
}

// K4: z = h1 @ w2. 8 rows/block, 512 threads: half 0 -> k in [0,128),
// half 1 -> k in [128,256); LDS partial combine.
__global__ __launch_bounds__(512) void k4_z(
    const float* __restrict__ h1, const float* __restrict__ w2_e,
    const float* __restrict__ w2_d, float* __restrict__ zz)
{
  const int blk = blockIdx.x, b = blockIdx.y;
  const int t = threadIdx.x;
  const int j = t & 255, half = t >> 8;
  const float* w2 = b ? w2_d : w2_e;
  const float* h1b = h1 + (size_t)b * MV * HD + (size_t)blk * 8 * HD;
  __shared__ float tile[8][HD];
  __shared__ float part[8][HD];
  {
    float4* t4 = (float4*)tile;
    const float4* s4 = (const float4*)h1b;
    t4[t] = s4[t];
  }
  __syncthreads();
  float acc[8];
#pragma unroll
  for (int r = 0; r < 8; ++r) acc[r] = 0.f;
  const int k0 = half * 128;
  for (int k = k0; k < k0 + 128; k += 4) {
    float wa = w2[(size_t)(k + 0) * HD + j];
    float wb = w2[(size_t)(k + 1) * HD + j];
    float wc = w2[(size_t)(k + 2) * HD + j];
    float wd = w2[(size_t)(k + 3) * HD + j];
#pragma unroll
    for (int r = 0; r < 8; ++r) {
      float4 tv = *(const float4*)&tile[r][k];
      acc[r] = fmaf(tv.x, wa, acc[r]);
      acc[r] = fmaf(tv.y, wb, acc[r]);
      acc[r] = fmaf(tv.z, wc, acc[r]);
      acc[r] = fmaf(tv.w, wd, acc[r]);
    }
  }
  if (half == 1) {
#pragma unroll
    for (int r = 0; r < 8; ++r) part[r][j] = acc[r];
  }
  __syncthreads();
  if (half == 0) {
    float* zb = zz + (size_t)b * MV * HD + (size_t)blk * 8 * HD;
#pragma unroll
    for (int r = 0; r < 8; ++r) zb[r * HD + j] = acc[r] + part[r][j];
  }
}

// K5: prior[r,:] = (sparse_ehr(r)@z_e + b2_e) - inter*(sparse_ddi(r)@z_d + b2_d);
//     s1[r] = query . prior[r,:]
__global__ __launch_bounds__(256) void k5_prior(
    const float* __restrict__ zz, const int* __restrict__ cnt_g,
    const int* __restrict__ cols_g, const float* __restrict__ vals_g,
    const float* __restrict__ b2_e, const float* __restrict__ b2_d,
    const float* __restrict__ inter, const float* __restrict__ queries,
    float* __restrict__ prior, float* __restrict__ s1)
{
  const int r = blockIdx.x, j = threadIdx.x;
  __shared__ float red[256];
  float acc_e = b2_e[j];
  {
    const int ne = cnt_g[r];
    const int* ce = cols_g + (size_t)r * MAXNZ;
    const float* ve = vals_g + (size_t)r * MAXNZ;
    for (int k = 0; k < ne; ++k)
      acc_e = fmaf(ve[k], zz[(size_t)ce[k] * HD + j], acc_e);
  }
  float acc_d = b2_d[j];
  {
    const int nd = cnt_g[MV + r];
    const int* cd = cols_g + (size_t)(MV + r) * MAXNZ;
    const float* vd = vals_g + (size_t)(MV + r) * MAXNZ;
    const float* zd = zz + (size_t)MV * HD;
    for (int k = 0; k < nd; ++k)
      acc_d = fmaf(vd[k], zd[(size_t)cd[k] * HD + j], acc_d);
  }
  const float pr = acc_e - inter[0] * acc_d;
  prior[(size_t)r * HD + j] = pr;
  red[j] = queries[31 * HD + j] * pr;
  __syncthreads();
  for (int s = 128; s > 0; s >>= 1) {
    if (j < s) red[j] += red[j + s];
    __syncthreads();
  }
  if (j == 0) s1[r] = red[0];
}

// K6a: w_emb = softmax(s1) over 4096; visit_w = softmax(query . queries[t<31])
__global__ __launch_bounds__(1024) void k6a_softmax(
    const float* __restrict__ s1, const float* __restrict__ queries,
    float* __restrict__ w_emb, float* __restrict__ visw)
{
  const int j = threadIdx.x;
  __shared__ float red[1024];
  __shared__ float s2[31];
  float m = -1e30f;
  for (int i = j; i < MV; i += 1024) m = fmaxf(m, s1[i]);
  red[j] = m;
  __syncthreads();
  for (int s = 512; s > 0; s >>= 1) {
    if (j < s) red[j] = fmaxf(red[j], red[j + s]);
    __syncthreads();
  }
  const float mx = red[0];
  __syncthreads();
  float sum = 0.f;
  for (int i = j; i < MV; i += 1024) sum += __expf(s1[i] - mx);
  red[j] = sum;
  __syncthreads();
  for (int s = 512; s > 0; s >>= 1) {
    if (j < s) red[j] += red[j + s];
    __syncthreads();
  }
  const float inv = 1.f / red[0];
  for (int i = j; i < MV; i += 1024) w_emb[i] = __expf(s1[i] - mx) * inv;

  if (j < 31) {
    float acc = 0.f;
    for (int k = 0; k < HD; ++k)
      acc = fmaf(queries[31 * HD + k], queries[(size_t)j * HD + k], acc);
    s2[j] = acc;
  }
  __syncthreads();
  if (j == 0) {
    float mm = -1e30f;
    for (int t = 0; t < 31; ++t) mm = fmaxf(mm, s2[t]);
    float ss = 0.f;
    for (int t = 0; t < 31; ++t) ss += __expf(s2[t] - mm);
    const float is = 1.f / ss;
    for (int t = 0; t < 31; ++t) visw[t] = __expf(s2[t] - mm) * is;
  }
}

// K6b: wv[m] = sum_t visit_w[t] * [m in med_codes[t]]  (set semantics)
__global__ __launch_bounds__(1024) void k6b_wv(
    const int* __restrict__ med, const float* __restrict__ visw,
    float* __restrict__ wv)
{
  __shared__ int mc[31 * LM_];
  __shared__ float vw[31];
  const int j = threadIdx.x;
  if (j < 31 * LM_) mc[j] = med[j];
  if (j < 31) vw[j] = visw[j];
  __syncthreads();
  const int m = blockIdx.x * 1024 + j;
  float acc = 0.f;
  for (int t = 0; t < 31; ++t) {
    bool found = false;
#pragma unroll
    for (int l = 0; l < LM_; ++l) found = found || (mc[t * LM_ + l] == m);
    if (found) acc += vw[t];
  }
  wv[m] = acc;
}

// K7: 8 rows/block, 512 threads: half 0 accumulates prior@Wa, half 1 prior@Wb;
// LDS partial combine: out = we*A + wv*B + proj_b.
__global__ __launch_bounds__(512) void k7_out(
    const float* __restrict__ prior, const float* __restrict__ w_emb,
    const float* __restrict__ wv, const float* __restrict__ proj_w,
    const float* __restrict__ proj_b, float* __restrict__ out)
{
  const int blk = blockIdx.x;
  const int t = threadIdx.x;
  const int j = t & 255, half = t >> 8;
  const int r0 = blk * 8;
  __shared__ float tile[8][HD];
  __shared__ float part[8][HD];
  __shared__ float we[8], wvv[8];
  {
    float4* t4 = (float4*)tile;
    const float4* s4 = (const float4*)(prior + (size_t)r0 * HD);
    t4[t] = s4[t];
  }
  if (t < 8) { we[t] = w_emb[r0 + t]; wvv[t] = wv[r0 + t]; }
  __syncthreads();
  const float* wmat = proj_w + (size_t)half * HD * HD;
  float acc[8];
#pragma unroll
  for (int r = 0; r < 8; ++r) acc[r] = 0.f;
  for (int k = 0; k < HD; k += 4) {
    float wa = wmat[(size_t)(k + 0) * HD + j];
    float wb = wmat[(size_t)(k + 1) * HD + j];
    float wc = wmat[(size_t)(k + 2) * HD + j];
    float wd = wmat[(size_t)(k + 3) * HD + j];
#pragma unroll
    for (int r = 0; r < 8; ++r) {
      float4 tv = *(const float4*)&tile[r][k];
      acc[r] = fmaf(tv.x, wa, acc[r]);
      acc[r] = fmaf(tv.y, wb, acc[r]);
      acc[r] = fmaf(tv.z, wc, acc[r]);
      acc[r] = fmaf(tv.w, wd, acc[r]);
    }
  }
  if (half == 1) {
#pragma unroll
    for (int r = 0; r < 8; ++r) part[r][j] = acc[r];
  }
  __syncthreads();
  if (half == 0) {
    const float pb = proj_b[j];
#pragma unroll
    for (int r = 0; r < 8; ++r)
      out[(size_t)(r0 + r) * HD + j] = we[r] * acc[r] + wvv[r] * part[r][j] + pb;
  }
}

extern "C" void kernel_launch(void* const* d_in, const int* in_sizes, int n_in,
                              void* d_out, int out_size, void* d_ws, size_t ws_size,
                              hipStream_t stream) {
  const int* diag_codes = (const int*)d_in[0];
  const int* proc_codes = (const int*)d_in[1];
  const int* med_codes  = (const int*)d_in[2];
  const float* diag_emb = (const float*)d_in[3];
  const float* proc_emb = (const float*)d_in[4];
  const float* wih_d = (const float*)d_in[5];
  const float* whh_d = (const float*)d_in[6];
  const float* bih_d = (const float*)d_in[7];
  const float* bhh_d = (const float*)d_in[8];
  const float* wih_p = (const float*)d_in[9];
  const float* whh_p = (const float*)d_in[10];
  const float* bih_p = (const float*)d_in[11];
  const float* bhh_p = (const float*)d_in[12];
  const float* q_w = (const float*)d_in[13];
  const float* q_b = (const float*)d_in[14];
  const float* adj_ehr = (const float*)d_in[15];
  const float* adj_ddi = (const float*)d_in[16];
  const float* w1_ehr = (const float*)d_in[17];
  const float* b1_ehr = (const float*)d_in[18];
  const float* w2_ehr = (const float*)d_in[19];
  const float* b2_ehr = (const float*)d_in[20];
  const float* w1_ddi = (const float*)d_in[21];
  const float* b1_ddi = (const float*)d_in[22];
  const float* w2_ddi = (const float*)d_in[23];
  const float* b2_ddi = (const float*)d_in[24];
  const float* inter = (const float*)d_in[25];
  const float* proj_w = (const float*)d_in[26];
  const float* proj_b = (const float*)d_in[27];
  float* out = (float*)d_out;

  float* ws = (float*)d_ws;
  size_t off = 0;
  float* GI      = ws + off; off += 2 * TT * 768;        // 49152
  float* feats   = ws + off; off += TT * 512;            // 16384
  float* queries = ws + off; off += TT * HD;             // 8192
  float* h1      = ws + off; off += 2 * (size_t)MV * HD; // 2M
  float* zz      = ws + off; off += 2 * (size_t)MV * HD; // 2M
  float* prior   = ws + off; off += (size_t)MV * HD;     // 1M
  float* s1      = ws + off; off += MV;
  float* w_emb   = ws + off; off += MV;
  float* visw    = ws + off; off += 32;
  float* wv      = ws + off; off += MV;
  int*   cnt_g   = (int*)(ws + off); off += 2 * MV;
  int*   cols_g  = (int*)(ws + off); off += 2 * (size_t)MV * MAXNZ;
  float* vals_g  = ws + off; off += 2 * (size_t)MV * MAXNZ;
  h8*    wt      = (h8*)(ws + off); off += 2 * 32 * 768 * 4; // 786432 B
  (void)ws_size; (void)in_sizes; (void)n_in; (void)out_size;

  k0_cvt<<<dim3(32, 2), 768, 0, stream>>>(whh_d, whh_p, wt);
  k1_embed_gi<<<dim3(TT, 2), 768, 0, stream>>>(diag_codes, proc_codes, diag_emb,
      proc_emb, wih_d, bih_d, wih_p, bih_p, GI);
  k3_scan<<<2 * MV / 8, 512, 0, stream>>>(adj_ehr, adj_ddi, w1_ehr, b1_ehr,
      w1_ddi, b1_ddi, h1, cnt_g, cols_g, vals_g);
  k2_gru<<<2, 256, 0, stream>>>(GI, wt, bhh_d, bhh_p, feats);
  k2b_queries<<<TT, 256, 0, stream>>>(feats, q_w, q_b, queries);
  k4_z<<<dim3(MV / 8, 2), 512, 0, stream>>>(h1, w2_ehr, w2_ddi, zz);
  k5_prior<<<MV, 256, 0, stream>>>(zz, cnt_g, cols_g, vals_g, b2_ehr, b2_ddi,
      inter, queries, prior, s1);
  k6a_softmax<<<1, 1024, 0, stream>>>(s1, queries, w_emb, visw);
  k6b_wv<<<MV / 1024, 1024, 0, stream>>>(med_codes, visw, wv);
  k7_out<<<MV / 8, 512, 0, stream>>>(prior, w_emb, wv, proj_w, proj_b, out);
}

// Round 6
// 196.836 us; speedup vs baseline: 1.3103x; 1.3103x over previous
//
#include <hip/hip_runtime.h>
#include <hip/hip_bf16.h>

// Sizes
#define HD   256
#define TT   32
#define MV   4096
#define LD_  24
#define LP_  12
#define LM_  20
#define MAXNZ 96
#define SCAN_WPB 12   // scan rows (waves) per fused block

typedef _Float16 h2v __attribute__((ext_vector_type(2)));
typedef _Float16 h8  __attribute__((ext_vector_type(8)));

__device__ __forceinline__ float fdot2(h2v a, h2v b, float c) {
#if __has_builtin(__builtin_amdgcn_fdot2)
  return __builtin_amdgcn_fdot2(a, b, c, false);
#else
  return c + (float)a[0] * (float)b[0] + (float)a[1] * (float)b[1];
#endif
}

#define PIN2(x) { float _t = __builtin_bit_cast(float, x); \
                  asm volatile("" : "+v"(_t));             \
                  x = __builtin_bit_cast(h2v, _t); }

// K0: whh (f32, 768x256 row-major) -> f16, transposed chunk layout:
// wt[b][i][row] = h8 of whh[b][row][8i..8i+7]
__global__ __launch_bounds__(768) void k0_cvt(
    const float* __restrict__ whh_d, const float* __restrict__ whh_p,
    h8* __restrict__ wt)
{
  const int i = blockIdx.x, b = blockIdx.y, g = threadIdx.x;
  const float* whh = b ? whh_p : whh_d;
  const float* src = whh + (size_t)g * HD + 8 * i;
  h8 v;
#pragma unroll
  for (int e = 0; e < 8; ++e) v[e] = (_Float16)src[e];
  wt[((size_t)b * 32 + i) * 768 + g] = v;
}

// K1: seq = sum of embedding rows; GI[b][t][g] = bih[g] + sum_k wih[g,k]*seq[k]
__global__ __launch_bounds__(768) void k1_embed_gi(
    const int* __restrict__ dc, const int* __restrict__ pc,
    const float* __restrict__ demb, const float* __restrict__ pemb,
    const float* __restrict__ wih_d, const float* __restrict__ bih_d,
    const float* __restrict__ wih_p, const float* __restrict__ bih_p,
    float* __restrict__ GI)
{
  const int t = blockIdx.x, b = blockIdx.y;
  const int* codes = b ? pc : dc;
  const int L = b ? LP_ : LD_;
  const float* emb = b ? pemb : demb;
  const float* wih = b ? wih_p : wih_d;
  const float* bih = b ? bih_p : bih_d;
  __shared__ float s[HD];
  const int j = threadIdx.x;
  if (j < HD) {
    float acc = 0.f;
    for (int l = 0; l < L; ++l) acc += emb[(size_t)codes[t * L + l] * HD + j];
    s[j] = acc;
  }
  __syncthreads();
  const int g = j;
  float acc = bih[g];
  const float* wr = wih + (size_t)g * HD;
  for (int k = 0; k < HD; k += 4) {
    float4 w4 = *(const float4*)(wr + k);
    acc = fmaf(w4.x, s[k], acc);
    acc = fmaf(w4.y, s[k + 1], acc);
    acc = fmaf(w4.z, s[k + 2], acc);
    acc = fmaf(w4.w, s[k + 3], acc);
  }
  GI[((size_t)b * TT + t) * 768 + g] = acc;
}

// K23 fused: blocks 0-1 run the sequential GRU (one gate-row per thread,
// w[128] register-resident under waves_per_eu(3,3) => 512/3 = ~170 VGPR
// budget); blocks 2.. stream adj rows (one wave per row, shfl prefix scan).
// The 2 GRU blocks hide under the scan's HBM streaming on the other CUs.
__global__ __launch_bounds__(768)
__attribute__((amdgpu_waves_per_eu(3, 3)))
void k23_fused(
    const float* __restrict__ GI, const h8* __restrict__ wt,
    const float* __restrict__ bhh_d, const float* __restrict__ bhh_p,
    float* __restrict__ feats,
    const float* __restrict__ adj_e, const float* __restrict__ adj_d,
    const float* __restrict__ w1_e, const float* __restrict__ b1_e,
    const float* __restrict__ w1_d, const float* __restrict__ b1_d,
    float* __restrict__ h1, int* __restrict__ cnt_g,
    int* __restrict__ cols_g, float* __restrict__ vals_g)
{
  __shared__ h8 hbuf[2][32];          // GRU: h as packed f16, double-buffered
  __shared__ float ghs[768];          // GRU: per-row h-dots
  __shared__ int   scols[SCAN_WPB][MAXNZ];
  __shared__ float svals[SCAN_WPB][MAXNZ];

  if (blockIdx.x < 2) {
    // ---------------- GRU ----------------
    const int b = blockIdx.x, g = threadIdx.x;
    const float* gi = GI + (size_t)b * TT * 768;
    const float* bhh = b ? bhh_p : bhh_d;

    h2v w[128];
    {
      const h8* wrow = wt + (size_t)b * 32 * 768 + g;
#pragma unroll
      for (int i = 0; i < 32; ++i) {
        union { h8 v; h2v p[4]; } u;
        u.v = wrow[(size_t)i * 768];
        w[4 * i + 0] = u.p[0];
        w[4 * i + 1] = u.p[1];
        w[4 * i + 2] = u.p[2];
        w[4 * i + 3] = u.p[3];
      }
    }
#pragma unroll
    for (int i = 0; i < 128; ++i) PIN2(w[i])

    const float bh = bhh[g];
    float hreg = 0.f;
    if (g < HD) ((_Float16*)&hbuf[0][0])[g] = (_Float16)0.f;
    __syncthreads();

    for (int t = 0; t < TT; ++t) {
      // prefetch gate inputs (only combine threads need them); L2-resident,
      // latency hidden under the dot loop
      const float* git = gi + t * 768;
      float ir = 0.f, iz = 0.f, inn = 0.f;
      if (g < HD) { ir = git[g]; iz = git[HD + g]; inn = git[2 * HD + g]; }

      const h8* hb = hbuf[t & 1];
      float d0 = 0.f, d1 = 0.f, d2 = 0.f, d3 = 0.f;
#pragma unroll
      for (int i = 0; i < 32; ++i) {
        union { h8 v; h2v p[4]; } u;
        u.v = hb[i];
        d0 = fdot2(w[4 * i + 0], u.p[0], d0);
        d1 = fdot2(w[4 * i + 1], u.p[1], d1);
        d2 = fdot2(w[4 * i + 2], u.p[2], d2);
        d3 = fdot2(w[4 * i + 3], u.p[3], d3);
      }
      ghs[g] = (d0 + d1) + (d2 + d3) + bh;
      __syncthreads();
      if (g < HD) {
        const float hr = ghs[g], hz = ghs[HD + g], hn = ghs[2 * HD + g];
        const float r = 1.f / (1.f + __expf(-(ir + hr)));
        const float z = 1.f / (1.f + __expf(-(iz + hz)));
        const float n = tanhf(inn + r * hn);
        hreg = (1.f - z) * n + z * hreg;
        ((_Float16*)&hbuf[(t & 1) ^ 1][0])[g] = (_Float16)hreg;
        feats[(size_t)t * 512 + b * HD + g] = hreg;
      }
      __syncthreads();
    }
    return;
  }

  // ---------------- adjacency scan ----------------
  const int w = threadIdx.x >> 6, lane = threadIdx.x & 63;
  const int rg = (blockIdx.x - 2) * SCAN_WPB + w;   // [0, 8192)
  if (rg >= 2 * MV) return;
  const int bsel = rg >> 12;
  const int r = rg & (MV - 1);
  const float* adj = (bsel ? adj_d : adj_e) + (size_t)r * MV;
  const float* w1 = bsel ? w1_d : w1_e;
  const float* b1 = bsel ? b1_d : b1_e;

  float4 ev[16];
#pragma unroll
  for (int c = 0; c < 16; ++c)
    ev[c] = *(const float4*)(adj + c * 256 + lane * 4);

  int cl = 0;
#pragma unroll
  for (int c = 0; c < 16; ++c)
    cl += (ev[c].x != 0.f) + (ev[c].y != 0.f) + (ev[c].z != 0.f) + (ev[c].w != 0.f);

  int pref = cl;
#pragma unroll
  for (int ofs = 1; ofs < 64; ofs <<= 1) {
    int v = __shfl_up(pref, ofs, 64);
    if (lane >= ofs) pref += v;
  }
  const int total = __shfl(pref, 63, 64);
  int pos = pref - cl;  // exclusive prefix

#pragma unroll
  for (int c = 0; c < 16; ++c) {
    const float vv[4] = {ev[c].x, ev[c].y, ev[c].z, ev[c].w};
#pragma unroll
    for (int e = 0; e < 4; ++e) {
      if (vv[e] != 0.f) {
        if (pos < MAXNZ) {
          scols[w][pos] = c * 256 + lane * 4 + e;
          svals[w][pos] = vv[e];
        }
        ++pos;
      }
    }
  }
  const int n = total > MAXNZ ? MAXNZ : total;
  // wave-synchronous LDS (single wave produces & consumes) -> no barrier

  float4 acc = *(const float4*)(b1 + lane * 4);
  for (int k = 0; k < n; ++k) {
    const int col = scols[w][k];
    const float v = svals[w][k];
    const float4 wv4 = *(const float4*)(w1 + (size_t)col * HD + lane * 4);
    acc.x = fmaf(v, wv4.x, acc.x);
    acc.y = fmaf(v, wv4.y, acc.y);
    acc.z = fmaf(v, wv4.z, acc.z);
    acc.w = fmaf(v, wv4.w, acc.w);
  }
  float4 hro;
  hro.x = fmaxf(acc.x, 0.f); hro.y = fmaxf(acc.y, 0.f);
  hro.z = fmaxf(acc.z, 0.f); hro.w = fmaxf(acc.w, 0.f);
  *(float4*)(h1 + (size_t)rg * HD + lane * 4) = hro;

  if (lane == 0) cnt_g[rg] = n;
  for (int k = lane; k < n; k += 64) {
    cols_g[(size_t)rg * MAXNZ + k] = scols[w][k];
    vals_g[(size_t)rg * MAXNZ + k] = svals[w][k];
  }
}

// K2b: queries[t,j] = q_b[j] + sum_k relu(feats[t,k]) * q_w[k,j]
__global__ __launch_bounds__(256) void k2b_queries(
    const float* __restrict__ feats, const float* __restrict__ q_w,
    const float* __restrict__ q_b, float* __restrict__ queries)
{
  const int t = blockIdx.x, j = threadIdx.x;
  __shared__ float f[512];
  f[j] = fmaxf(feats[(size_t)t * 512 + j], 0.f);
  f[j + 256] = fmaxf(feats[(size_t)t * 512 + 256 + j], 0.f);
  __syncthreads();
  float acc = q_b[j];
  for (int k = 0; k < 512; ++k) acc = fmaf(f[k], q_w[(size_t)k * HD + j], acc);
  queries[(size_t)t * HD + j] = acc;
}

// K4: z = h1 @ w2. 8 rows/block, 512 threads, k-split halves + LDS combine.
__global__ __launch_bounds__(512) void k4_z(
    const float* __restrict__ h1, const float* __restrict__ w2_e,
    const float* __restrict__ w2_d, float* __restrict__ zz)
{
  const int blk = blockIdx.x, b = blockIdx.y;
  const int t = threadIdx.x;
  const int j = t & 255, half = t >> 8;
  const float* w2 = b ? w2_d : w2_e;
  const float* h1b = h1 + (size_t)b * MV * HD + (size_t)blk * 8 * HD;
  __shared__ float tile[8][HD];
  __shared__ float part[8][HD];
  {
    float4* t4 = (float4*)tile;
    const float4* s4 = (const float4*)h1b;
    t4[t] = s4[t];
  }
  __syncthreads();
  float acc[8];
#pragma unroll
  for (int r = 0; r < 8; ++r) acc[r] = 0.f;
  const int k0 = half * 128;
  for (int k = k0; k < k0 + 128; k += 4) {
    float wa = w2[(size_t)(k + 0) * HD + j];
    float wb = w2[(size_t)(k + 1) * HD + j];
    float wc = w2[(size_t)(k + 2) * HD + j];
    float wd = w2[(size_t)(k + 3) * HD + j];
#pragma unroll
    for (int r = 0; r < 8; ++r) {
      float4 tv = *(const float4*)&tile[r][k];
      acc[r] = fmaf(tv.x, wa, acc[r]);
      acc[r] = fmaf(tv.y, wb, acc[r]);
      acc[r] = fmaf(tv.z, wc, acc[r]);
      acc[r] = fmaf(tv.w, wd, acc[r]);
    }
  }
  if (half == 1) {
#pragma unroll
    for (int r = 0; r < 8; ++r) part[r][j] = acc[r];
  }
  __syncthreads();
  if (half == 0) {
    float* zb = zz + (size_t)b * MV * HD + (size_t)blk * 8 * HD;
#pragma unroll
    for (int r = 0; r < 8; ++r) zb[r * HD + j] = acc[r] + part[r][j];
  }
}

// K5: prior[r,:] = (sparse_ehr(r)@z_e + b2_e) - inter*(sparse_ddi(r)@z_d + b2_d);
//     s1[r] = query . prior[r,:]
__global__ __launch_bounds__(256) void k5_prior(
    const float* __restrict__ zz, const int* __restrict__ cnt_g,
    const int* __restrict__ cols_g, const float* __restrict__ vals_g,
    const float* __restrict__ b2_e, const float* __restrict__ b2_d,
    const float* __restrict__ inter, const float* __restrict__ queries,
    float* __restrict__ prior, float* __restrict__ s1)
{
  const int r = blockIdx.x, j = threadIdx.x;
  __shared__ float red[256];
  float acc_e = b2_e[j];
  {
    const int ne = cnt_g[r];
    const int* ce = cols_g + (size_t)r * MAXNZ;
    const float* ve = vals_g + (size_t)r * MAXNZ;
    for (int k = 0; k < ne; ++k)
      acc_e = fmaf(ve[k], zz[(size_t)ce[k] * HD + j], acc_e);
  }
  float acc_d = b2_d[j];
  {
    const int nd = cnt_g[MV + r];
    const int* cd = cols_g + (size_t)(MV + r) * MAXNZ;
    const float* vd = vals_g + (size_t)(MV + r) * MAXNZ;
    const float* zd = zz + (size_t)MV * HD;
    for (int k = 0; k < nd; ++k)
      acc_d = fmaf(vd[k], zd[(size_t)cd[k] * HD + j], acc_d);
  }
  const float pr = acc_e - inter[0] * acc_d;
  prior[(size_t)r * HD + j] = pr;
  red[j] = queries[31 * HD + j] * pr;
  __syncthreads();
  for (int s = 128; s > 0; s >>= 1) {
    if (j < s) red[j] += red[j + s];
    __syncthreads();
  }
  if (j == 0) s1[r] = red[0];
}

// K6a: w_emb = softmax(s1) over 4096; visit_w = softmax(query . queries[t<31])
__global__ __launch_bounds__(1024) void k6a_softmax(
    const float* __restrict__ s1, const float* __restrict__ queries,
    float* __restrict__ w_emb, float* __restrict__ visw)
{
  const int j = threadIdx.x;
  __shared__ float red[1024];
  __shared__ float s2[31];
  float m = -1e30f;
  for (int i = j; i < MV; i += 1024) m = fmaxf(m, s1[i]);
  red[j] = m;
  __syncthreads();
  for (int s = 512; s > 0; s >>= 1) {
    if (j < s) red[j] = fmaxf(red[j], red[j + s]);
    __syncthreads();
  }
  const float mx = red[0];
  __syncthreads();
  float sum = 0.f;
  for (int i = j; i < MV; i += 1024) sum += __expf(s1[i] - mx);
  red[j] = sum;
  __syncthreads();
  for (int s = 512; s > 0; s >>= 1) {
    if (j < s) red[j] += red[j + s];
    __syncthreads();
  }
  const float inv = 1.f / red[0];
  for (int i = j; i < MV; i += 1024) w_emb[i] = __expf(s1[i] - mx) * inv;

  if (j < 31) {
    float acc = 0.f;
    for (int k = 0; k < HD; ++k)
      acc = fmaf(queries[31 * HD + k], queries[(size_t)j * HD + k], acc);
    s2[j] = acc;
  }
  __syncthreads();
  if (j == 0) {
    float mm = -1e30f;
    for (int t = 0; t < 31; ++t) mm = fmaxf(mm, s2[t]);
    float ss = 0.f;
    for (int t = 0; t < 31; ++t) ss += __expf(s2[t] - mm);
    const float is = 1.f / ss;
    for (int t = 0; t < 31; ++t) visw[t] = __expf(s2[t] - mm) * is;
  }
}

// K6b: wv[m] = sum_t visit_w[t] * [m in med_codes[t]]  (set semantics)
__global__ __launch_bounds__(1024) void k6b_wv(
    const int* __restrict__ med, const float* __restrict__ visw,
    float* __restrict__ wv)
{
  __shared__ int mc[31 * LM_];
  __shared__ float vw[31];
  const int j = threadIdx.x;
  if (j < 31 * LM_) mc[j] = med[j];
  if (j < 31) vw[j] = visw[j];
  __syncthreads();
  const int m = blockIdx.x * 1024 + j;
  float acc = 0.f;
  for (int t = 0; t < 31; ++t) {
    bool found = false;
#pragma unroll
    for (int l = 0; l < LM_; ++l) found = found || (mc[t * LM_ + l] == m);
    if (found) acc += vw[t];
  }
  wv[m] = acc;
}

// K7: 8 rows/block, 512 threads: half 0 = prior@Wa, half 1 = prior@Wb;
// LDS combine: out = we*A + wv*B + proj_b.
__global__ __launch_bounds__(512) void k7_out(
    const float* __restrict__ prior, const float* __restrict__ w_emb,
    const float* __restrict__ wv, const float* __restrict__ proj_w,
    const float* __restrict__ proj_b, float* __restrict__ out)
{
  const int blk = blockIdx.x;
  const int t = threadIdx.x;
  const int j = t & 255, half = t >> 8;
  const int r0 = blk * 8;
  __shared__ float tile[8][HD];
  __shared__ float part[8][HD];
  __shared__ float we[8], wvv[8];
  {
    float4* t4 = (float4*)tile;
    const float4* s4 = (const float4*)(prior + (size_t)r0 * HD);
    t4[t] = s4[t];
  }
  if (t < 8) { we[t] = w_emb[r0 + t]; wvv[t] = wv[r0 + t]; }
  __syncthreads();
  const float* wmat = proj_w + (size_t)half * HD * HD;
  float acc[8];
#pragma unroll
  for (int r = 0; r < 8; ++r) acc[r] = 0.f;
  for (int k = 0; k < HD; k += 4) {
    float wa = wmat[(size_t)(k + 0) * HD + j];
    float wb = wmat[(size_t)(k + 1) * HD + j];
    float wc = wmat[(size_t)(k + 2) * HD + j];
    float wd = wmat[(size_t)(k + 3) * HD + j];
#pragma unroll
    for (int r = 0; r < 8; ++r) {
      float4 tv = *(const float4*)&tile[r][k];
      acc[r] = fmaf(tv.x, wa, acc[r]);
      acc[r] = fmaf(tv.y, wb, acc[r]);
      acc[r] = fmaf(tv.z, wc, acc[r]);
      acc[r] = fmaf(tv.w, wd, acc[r]);
    }
  }
  if (half == 1) {
#pragma unroll
    for (int r = 0; r < 8; ++r) part[r][j] = acc[r];
  }
  __syncthreads();
  if (half == 0) {
    const float pb = proj_b[j];
#pragma unroll
    for (int r = 0; r < 8; ++r)
      out[(size_t)(r0 + r) * HD + j] = we[r] * acc[r] + wvv[r] * part[r][j] + pb;
  }
}

extern "C" void kernel_launch(void* const* d_in, const int* in_sizes, int n_in,
                              void* d_out, int out_size, void* d_ws, size_t ws_size,
                              hipStream_t stream) {
  const int* diag_codes = (const int*)d_in[0];
  const int* proc_codes = (const int*)d_in[1];
  const int* med_codes  = (const int*)d_in[2];
  const float* diag_emb = (const float*)d_in[3];
  const float* proc_emb = (const float*)d_in[4];
  const float* wih_d = (const float*)d_in[5];
  const float* whh_d = (const float*)d_in[6];
  const float* bih_d = (const float*)d_in[7];
  const float* bhh_d = (const float*)d_in[8];
  const float* wih_p = (const float*)d_in[9];
  const float* whh_p = (const float*)d_in[10];
  const float* bih_p = (const float*)d_in[11];
  const float* bhh_p = (const float*)d_in[12];
  const float* q_w = (const float*)d_in[13];
  const float* q_b = (const float*)d_in[14];
  const float* adj_ehr = (const float*)d_in[15];
  const float* adj_ddi = (const float*)d_in[16];
  const float* w1_ehr = (const float*)d_in[17];
  const float* b1_ehr = (const float*)d_in[18];
  const float* w2_ehr = (const float*)d_in[19];
  const float* b2_ehr = (const float*)d_in[20];
  const float* w1_ddi = (const float*)d_in[21];
  const float* b1_ddi = (const float*)d_in[22];
  const float* w2_ddi = (const float*)d_in[23];
  const float* b2_ddi = (const float*)d_in[24];
  const float* inter = (const float*)d_in[25];
  const float* proj_w = (const float*)d_in[26];
  const float* proj_b = (const float*)d_in[27];
  float* out = (float*)d_out;

  float* ws = (float*)d_ws;
  size_t off = 0;
  float* GI      = ws + off; off += 2 * TT * 768;        // 49152
  float* feats   = ws + off; off += TT * 512;            // 16384
  float* queries = ws + off; off += TT * HD;             // 8192
  float* h1      = ws + off; off += 2 * (size_t)MV * HD; // 2M
  float* zz      = ws + off; off += 2 * (size_t)MV * HD; // 2M
  float* prior   = ws + off; off += (size_t)MV * HD;     // 1M
  float* s1      = ws + off; off += MV;
  float* w_emb   = ws + off; off += MV;
  float* visw    = ws + off; off += 32;
  float* wv      = ws + off; off += MV;
  int*   cnt_g   = (int*)(ws + off); off += 2 * MV;
  int*   cols_g  = (int*)(ws + off); off += 2 * (size_t)MV * MAXNZ;
  float* vals_g  = ws + off; off += 2 * (size_t)MV * MAXNZ;
  h8*    wt      = (h8*)(ws + off); off += 2 * 32 * 768 * 4; // 786432 B
  (void)ws_size; (void)in_sizes; (void)n_in; (void)out_size;

  const int scan_blocks = (2 * MV + SCAN_WPB - 1) / SCAN_WPB;  // 683

  k0_cvt<<<dim3(32, 2), 768, 0, stream>>>(whh_d, whh_p, wt);
  k1_embed_gi<<<dim3(TT, 2), 768, 0, stream>>>(diag_codes, proc_codes, diag_emb,
      proc_emb, wih_d, bih_d, wih_p, bih_p, GI);
  k23_fused<<<2 + scan_blocks, 768, 0, stream>>>(GI, wt, bhh_d, bhh_p, feats,
      adj_ehr, adj_ddi, w1_ehr, b1_ehr, w1_ddi, b1_ddi,
      h1, cnt_g, cols_g, vals_g);
  k2b_queries<<<TT, 256, 0, stream>>>(feats, q_w, q_b, queries);
  k4_z<<<dim3(MV / 8, 2), 512, 0, stream>>>(h1, w2_ehr, w2_ddi, zz);
  k5_prior<<<MV, 256, 0, stream>>>(zz, cnt_g, cols_g, vals_g, b2_ehr, b2_ddi,
      inter, queries, prior, s1);
  k6a_softmax<<<1, 1024, 0, stream>>>(s1, queries, w_emb, visw);
  k6b_wv<<<MV / 1024, 1024, 0, stream>>>(med_codes, visw, wv);
  k7_out<<<MV / 8, 512, 0, stream>>>(prior, w_emb, wv, proj_w, proj_b, out);
}